// Round 2
// baseline (380.108 us; speedup 1.0000x reference)
//
#include <hip/hip_runtime.h>
#include <hip/hip_bf16.h>

#define D 1024
#define SLEN 2048
#define BS 16
#define MROWS (BS*SLEN)   // 32768

typedef __attribute__((ext_vector_type(8))) short short8;
typedef __attribute__((ext_vector_type(4))) float f32x4;

__device__ __forceinline__ short f2bf(float f) {
  __hip_bfloat16 h = __float2bfloat16(f);
  return __builtin_bit_cast(short, h);
}

#define GLOBAL_LOAD_LDS16(lds, g) \
  __builtin_amdgcn_global_load_lds((const __attribute__((address_space(1))) void*)(g), \
                                   (__attribute__((address_space(3))) void*)(lds), 16, 0, 0)

// ---------------- Kernel 1: Wk (k,n) fp32 -> blocked bf16 WkT ----------------
// Layout: WkT[(g*1024 + n)*8 + j] = bf16(Wk[(g*8+j)*1024 + n]),  g = 0..127.
// So 16B slot (g, n) holds B[n][k=g*8 .. g*8+7] — exactly one MFMA B k-unit,
// and staging lane n -> contiguous 16B = fully coalesced global_load_lds.
__global__ __launch_bounds__(256) void wk_prep(const float* __restrict__ Wk,
                                               short* __restrict__ WkT) {
  const int g = blockIdx.x;        // 0..127
  const int t = threadIdx.x;
#pragma unroll
  for (int it = 0; it < 4; ++it) {
    const int n = it*256 + t;
    short8 p;
#pragma unroll
    for (int j = 0; j < 8; ++j)
      p[j] = f2bf(Wk[(size_t)(g*8 + j)*D + n]);   // coalesced across lanes
    *(short8*)(WkT + ((size_t)g*D + n)*8) = p;    // coalesced 16B/lane
  }
}

// ---------------- Kernel 2: partial energy GEMM --------------------------
// e[m] += sum_{n in tile} tanh(relu((states@Wk)[m,n] + bk[n])) * We_k[n]
// Grid (4 N-tiles fast, 128 M-tiles). Block 256 thr = 4 waves (2M x 2N),
// block tile 128x256, wave tile 64x128 (4x8 MFMA 16x16x32, 128 acc regs).
// LDS [u][row] 16B-unit layout -> conflict-free ds_read_b128 / ds_write_b128.
__global__ __launch_bounds__(256) void energy_gemm(
    const float* __restrict__ states, const short* __restrict__ WkT,
    const float* __restrict__ bk, const float* __restrict__ We,
    float* __restrict__ eout)
{
  __shared__ short Al[2][512*8];    // 8 KB per buffer  (4 u x 128 rows)
  __shared__ short Bl[2][1024*8];   // 16 KB per buffer (4 u x 256 cols)

  const int tid  = threadIdx.x;
  const int w    = tid >> 6;        // wave 0..3
  const int lane = tid & 63;
  const int quad = lane >> 4;       // 0..3  (k-unit)
  const int l16  = lane & 15;
  const int wm   = w >> 1;          // 0..1
  const int wn   = w & 1;           // 0..1
  const int n0   = blockIdx.x * 256;
  const int m0   = blockIdx.y * 128;

  f32x4 acc[4][8];
#pragma unroll
  for (int mi = 0; mi < 4; ++mi)
#pragma unroll
    for (int ni = 0; ni < 8; ++ni)
      acc[mi][ni] = (f32x4){0.f, 0.f, 0.f, 0.f};

  // A staging: thread t owns slots {t, t+256}; slot s: u=s>>7, row=s&127.
  const int rA  = tid & 127;
  const int uA0 = tid >> 7;                       // 0/1 ; second slot u = uA0+2
  const float* AgA = states + (size_t)(m0 + rA)*D + uA0*8;
  const float* AgB = AgA + 16;                    // (uA0+2)*8
  // B staging: wave w stages u=w, 4 issues of 64 cols.
  const short* Bg = WkT + ((size_t)w*D + n0 + lane)*8;

#define STAGE_B(ic, buf)                                              \
  {                                                                   \
    _Pragma("unroll")                                                 \
    for (int j = 0; j < 4; ++j) {                                     \
      const short* g = Bg + ((size_t)(ic)*4*D + j*64)*8;              \
      GLOBAL_LOAD_LDS16(&Bl[buf][(w*256 + j*64)*8], g);               \
    }                                                                 \
  }

  // prologue: chunk 0 -> buffer 0
  STAGE_B(0, 0);
  {
    float4 x0 = *(const float4*)(AgA);
    float4 x1 = *(const float4*)(AgA + 4);
    float4 y0 = *(const float4*)(AgB);
    float4 y1 = *(const float4*)(AgB + 4);
    short8 pa, pb;
    pa[0]=f2bf(x0.x); pa[1]=f2bf(x0.y); pa[2]=f2bf(x0.z); pa[3]=f2bf(x0.w);
    pa[4]=f2bf(x1.x); pa[5]=f2bf(x1.y); pa[6]=f2bf(x1.z); pa[7]=f2bf(x1.w);
    pb[0]=f2bf(y0.x); pb[1]=f2bf(y0.y); pb[2]=f2bf(y0.z); pb[3]=f2bf(y0.w);
    pb[4]=f2bf(y1.x); pb[5]=f2bf(y1.y); pb[6]=f2bf(y1.z); pb[7]=f2bf(y1.w);
    *(short8*)(&Al[0][tid*8])       = pa;
    *(short8*)(&Al[0][(tid+256)*8]) = pb;
  }
  __syncthreads();

  for (int ic = 0; ic < 32; ++ic) {
    const int cb = ic & 1, nb = cb ^ 1;
    float4 x0, x1, y0, y1;
    if (ic < 31) {
      const int k0 = (ic + 1) * 32;
      x0 = *(const float4*)(AgA + k0);
      x1 = *(const float4*)(AgA + k0 + 4);
      y0 = *(const float4*)(AgB + k0);
      y1 = *(const float4*)(AgB + k0 + 4);
      STAGE_B(ic + 1, nb);
    }

    short8 fa[4], fb[8];
    const short* Ab = &Al[cb][0];
    const short* Bb = &Bl[cb][0];
#pragma unroll
    for (int mi = 0; mi < 4; ++mi)
      fa[mi] = *(const short8*)(Ab + (quad*128 + wm*64 + mi*16 + l16)*8);
#pragma unroll
    for (int ni = 0; ni < 8; ++ni)
      fb[ni] = *(const short8*)(Bb + (quad*256 + wn*128 + ni*16 + l16)*8);
#pragma unroll
    for (int mi = 0; mi < 4; ++mi)
#pragma unroll
      for (int ni = 0; ni < 8; ++ni)
        acc[mi][ni] = __builtin_amdgcn_mfma_f32_16x16x32_bf16(fa[mi], fb[ni], acc[mi][ni], 0, 0, 0);

    if (ic < 31) {   // convert+ds_write after MFMAs so global loads overlap compute
      short8 pa, pb;
      pa[0]=f2bf(x0.x); pa[1]=f2bf(x0.y); pa[2]=f2bf(x0.z); pa[3]=f2bf(x0.w);
      pa[4]=f2bf(x1.x); pa[5]=f2bf(x1.y); pa[6]=f2bf(x1.z); pa[7]=f2bf(x1.w);
      pb[0]=f2bf(y0.x); pb[1]=f2bf(y0.y); pb[2]=f2bf(y0.z); pb[3]=f2bf(y0.w);
      pb[4]=f2bf(y1.x); pb[5]=f2bf(y1.y); pb[6]=f2bf(y1.z); pb[7]=f2bf(y1.w);
      *(short8*)(&Al[nb][tid*8])       = pa;
      *(short8*)(&Al[nb][(tid+256)*8]) = pb;
    }
    __syncthreads();
  }

  // epilogue: f = tanh(relu(c + bk[n])) * We_k[n], reduce over this block's cols
  float esum[16];
#pragma unroll
  for (int q = 0; q < 16; ++q) esum[q] = 0.f;
#pragma unroll
  for (int ni = 0; ni < 8; ++ni) {
    const int n = n0 + wn*128 + ni*16 + l16;
    const float bkv = bk[n];
    const float wev = We[D + n];
#pragma unroll
    for (int mi = 0; mi < 4; ++mi)
#pragma unroll
      for (int r = 0; r < 4; ++r) {
        float x = acc[mi][ni][r] + bkv;
        x = fmaxf(x, 0.f);
        float ex = __expf(2.f * x);
        float th = 1.f - 2.f/(ex + 1.f);
        esum[mi*4 + r] += th * wev;
      }
  }
#pragma unroll
  for (int dd = 1; dd < 16; dd <<= 1)
#pragma unroll
    for (int q = 0; q < 16; ++q)
      esum[q] += __shfl_xor(esum[q], dd, 64);

  float* red = (float*)&Bl[0][0];   // [128 rows][2 wn]
  if (l16 == 0) {
#pragma unroll
    for (int mi = 0; mi < 4; ++mi)
#pragma unroll
      for (int r = 0; r < 4; ++r)
        red[(wm*64 + mi*16 + quad*4 + r)*2 + wn] = esum[mi*4 + r];
  }
  __syncthreads();
  if (tid < 128)
    atomicAdd(eout + m0 + tid, red[tid*2] + red[tid*2 + 1]);
}

// ---------------- Kernel 3: in-place row softmax over s=2048 ----------------
__global__ __launch_bounds__(256) void softmax_rows(float* __restrict__ e) {
  const int b = blockIdx.x, t = threadIdx.x;
  __shared__ float red[256];
  float v[8];
  float m = -1e30f;
#pragma unroll
  for (int j = 0; j < 8; ++j) {
    v[j] = e[(size_t)b*SLEN + j*256 + t];
    m = fmaxf(m, v[j]);
  }
  red[t] = m; __syncthreads();
  for (int s = 128; s > 0; s >>= 1) {
    if (t < s) red[t] = fmaxf(red[t], red[t+s]);
    __syncthreads();
  }
  m = red[0];
  __syncthreads();
  float sum = 0.f;
#pragma unroll
  for (int j = 0; j < 8; ++j) { v[j] = __expf(v[j] - m); sum += v[j]; }
  red[t] = sum; __syncthreads();
  for (int s = 128; s > 0; s >>= 1) {
    if (t < s) red[t] += red[t+s];
    __syncthreads();
  }
  const float inv = 1.f / red[0];
#pragma unroll
  for (int j = 0; j < 8; ++j)
    e[(size_t)b*SLEN + j*256 + t] = v[j] * inv;
}

// ---------------- Kernel 4: attn[b,d] = sum_s w[b,s]*states[b,s,d] ----------
// Block = (b, 64-row s-chunk); thread t owns d-cols 4t..4t+3 (float4, 16B/lane).
__global__ __launch_bounds__(256) void attn_reduce(
    const float* __restrict__ states, const float* __restrict__ wts,
    float* __restrict__ attn)
{
  const int sc = blockIdx.x;   // 0..31
  const int b  = blockIdx.y;   // 0..15
  const int t  = threadIdx.x;
  __shared__ float wsh[64];
  if (t < 64) wsh[t] = wts[(size_t)b*SLEN + sc*64 + t];
  __syncthreads();
  const float* sp = states + ((size_t)b*SLEN + sc*64)*D + t*4;
  float ax = 0.f, ay = 0.f, az = 0.f, aw = 0.f;
#pragma unroll 8
  for (int s = 0; s < 64; ++s) {
    float4 v = *(const float4*)(sp + (size_t)s*D);
    const float wv = wsh[s];
    ax = fmaf(wv, v.x, ax);
    ay = fmaf(wv, v.y, ay);
    az = fmaf(wv, v.z, az);
    aw = fmaf(wv, v.w, aw);
  }
  float* o = attn + (size_t)b*D + t*4;
  atomicAdd(o+0, ax); atomicAdd(o+1, ay);
  atomicAdd(o+2, az); atomicAdd(o+3, aw);
}

extern "C" void kernel_launch(void* const* d_in, const int* in_sizes, int n_in,
                              void* d_out, int out_size, void* d_ws, size_t ws_size,
                              hipStream_t stream) {
  // inputs: 0=query 1=states 2=Wq 3=bq 4=Wk 5=bk 6=We 7=be
  // q-path terms are constant per softmax row -> cancel; dead code.
  const float* states = (const float*)d_in[1];
  const float* Wk     = (const float*)d_in[4];
  const float* bk     = (const float*)d_in[5];
  const float* We     = (const float*)d_in[6];
  float* out = (float*)d_out;            // [0:32768) attn_weights, [32768:49152) attn
  short* WkT = (short*)d_ws;             // 2 MB bf16 blocked scratch

  (void)in_sizes; (void)n_in; (void)out_size; (void)ws_size;

  hipMemsetAsync(out, 0, (size_t)(MROWS + BS*D)*sizeof(float), stream);
  wk_prep<<<128, 256, 0, stream>>>(Wk, WkT);
  energy_gemm<<<dim3(4, MROWS/128), 256, 0, stream>>>(states, WkT, bk, We, out);
  softmax_rows<<<BS, 256, 0, stream>>>(out);
  attn_reduce<<<dim3(32, BS), 256, 0, stream>>>(states, out, out + MROWS);
}

// Round 3
// 379.965 us; speedup vs baseline: 1.0004x; 1.0004x over previous
//
#include <hip/hip_runtime.h>
#include <hip/hip_bf16.h>

#define D 1024
#define SLEN 2048
#define BS 16
#define MROWS (BS*SLEN)   // 32768

typedef __attribute__((ext_vector_type(8))) short short8;
typedef __attribute__((ext_vector_type(4))) float f32x4;

__device__ __forceinline__ short f2bf(float f) {
  __hip_bfloat16 h = __float2bfloat16(f);
  return __builtin_bit_cast(short, h);
}

#define GLOBAL_LOAD_LDS16(lds, g) \
  __builtin_amdgcn_global_load_lds((const __attribute__((address_space(1))) void*)(g), \
                                   (__attribute__((address_space(3))) void*)(lds), 16, 0, 0)

// ---------------- Kernel 1: Wk (k,n) fp32 -> blocked bf16 WkT ----------------
// WkT[(g*1024 + n)*8 + j] = bf16(Wk[(g*8+j)*1024 + n]), g=0..127.
// 16B slot (g,n) = B[n][k=g*8..g*8+7] = one MFMA B k-unit; staging lane n ->
// contiguous 16B, fully coalesced global_load_lds.
__global__ __launch_bounds__(256) void wk_prep(const float* __restrict__ Wk,
                                               short* __restrict__ WkT) {
  const int g = blockIdx.x;        // 0..127
  const int t = threadIdx.x;
#pragma unroll
  for (int it = 0; it < 4; ++it) {
    const int n = it*256 + t;
    short8 p;
#pragma unroll
    for (int j = 0; j < 8; ++j)
      p[j] = f2bf(Wk[(size_t)(g*8 + j)*D + n]);
    *(short8*)(WkT + ((size_t)g*D + n)*8) = p;
  }
}

// ---------------- Kernel 2: partial energy GEMM --------------------------
// e[m] += sum_{n in tile} tanh(relu((states@Wk)[m,n] + bk[n])) * We_k[n]
// m97 operating point: block 128x128, 256 thr = 4 waves (2x2), wave tile
// 64x64 (4x4 MFMA 16x16x32, 64 acc regs) -> 3 blocks/CU for barrier overlap.
// Grid 2048 1-D: m_tile = L&255, n_tile = L>>8 -> the 8 N-siblings of an
// M-tile share L%8 (same XCD under round-robin) -> A rows reused via L2.
// LDS [u][row] 16B-unit layout, conflict-free; 32 KB total.
__global__ __launch_bounds__(256, 3) void energy_gemm(
    const float* __restrict__ states, const short* __restrict__ WkT,
    const float* __restrict__ bk, const float* __restrict__ We,
    float* __restrict__ eout)
{
  __shared__ short Al[2][512*8];    // 8 KB per buffer (4 u x 128 rows)
  __shared__ short Bl[2][512*8];    // 8 KB per buffer (4 u x 128 cols)

  const int tid  = threadIdx.x;
  const int w    = tid >> 6;        // wave 0..3
  const int lane = tid & 63;
  const int quad = lane >> 4;       // k-unit 0..3
  const int l16  = lane & 15;
  const int wm   = w >> 1;          // 0..1
  const int wn   = w & 1;           // 0..1
  const int m0   = (blockIdx.x & 255) * 128;
  const int n0   = (blockIdx.x >> 8) * 128;

  f32x4 acc[4][4];
#pragma unroll
  for (int mi = 0; mi < 4; ++mi)
#pragma unroll
    for (int ni = 0; ni < 4; ++ni)
      acc[mi][ni] = (f32x4){0.f, 0.f, 0.f, 0.f};

  // A staging: thread t owns slots {t, t+256}; slot s: u=s>>7, row=s&127.
  const int rA  = tid & 127;
  const int uA0 = tid >> 7;                       // 0/1; second slot u=uA0+2
  const float* AgA = states + (size_t)(m0 + rA)*D + uA0*8;
  const float* AgB = AgA + 16;                    // (uA0+2)*8
  // B staging: wave w stages u=w, 2 issues of 64 cols.
  const short* Bg = WkT + ((size_t)w*D + n0 + lane)*8;

#define STAGE_B(ic, buf)                                              \
  {                                                                   \
    _Pragma("unroll")                                                 \
    for (int j = 0; j < 2; ++j) {                                     \
      const short* g = Bg + ((size_t)(ic)*4*D + j*64)*8;              \
      GLOBAL_LOAD_LDS16(&Bl[buf][(w*128 + j*64)*8], g);               \
    }                                                                 \
  }

  // prologue: chunk 0 -> buffer 0
  STAGE_B(0, 0);
  {
    float4 x0 = *(const float4*)(AgA);
    float4 x1 = *(const float4*)(AgA + 4);
    float4 y0 = *(const float4*)(AgB);
    float4 y1 = *(const float4*)(AgB + 4);
    short8 pa, pb;
    pa[0]=f2bf(x0.x); pa[1]=f2bf(x0.y); pa[2]=f2bf(x0.z); pa[3]=f2bf(x0.w);
    pa[4]=f2bf(x1.x); pa[5]=f2bf(x1.y); pa[6]=f2bf(x1.z); pa[7]=f2bf(x1.w);
    pb[0]=f2bf(y0.x); pb[1]=f2bf(y0.y); pb[2]=f2bf(y0.z); pb[3]=f2bf(y0.w);
    pb[4]=f2bf(y1.x); pb[5]=f2bf(y1.y); pb[6]=f2bf(y1.z); pb[7]=f2bf(y1.w);
    *(short8*)(&Al[0][tid*8])       = pa;
    *(short8*)(&Al[0][(tid+256)*8]) = pb;
  }
  __syncthreads();

  for (int ic = 0; ic < 32; ++ic) {
    const int cb = ic & 1, nb = cb ^ 1;
    float4 x0, x1, y0, y1;
    if (ic < 31) {
      const int k0 = (ic + 1) * 32;
      STAGE_B(ic + 1, nb);
      x0 = *(const float4*)(AgA + k0);
      x1 = *(const float4*)(AgA + k0 + 4);
      y0 = *(const float4*)(AgB + k0);
      y1 = *(const float4*)(AgB + k0 + 4);
    }

    short8 fa[4], fb[4];
    const short* Ab = &Al[cb][0];
    const short* Bb = &Bl[cb][0];
#pragma unroll
    for (int mi = 0; mi < 4; ++mi)
      fa[mi] = *(const short8*)(Ab + (quad*128 + wm*64 + mi*16 + l16)*8);
#pragma unroll
    for (int ni = 0; ni < 4; ++ni)
      fb[ni] = *(const short8*)(Bb + (quad*128 + wn*64 + ni*16 + l16)*8);
#pragma unroll
    for (int mi = 0; mi < 4; ++mi)
#pragma unroll
      for (int ni = 0; ni < 4; ++ni)
        acc[mi][ni] = __builtin_amdgcn_mfma_f32_16x16x32_bf16(fa[mi], fb[ni], acc[mi][ni], 0, 0, 0);

    if (ic < 31) {   // convert+ds_write after MFMAs so global loads overlap compute
      short8 pa, pb;
      pa[0]=f2bf(x0.x); pa[1]=f2bf(x0.y); pa[2]=f2bf(x0.z); pa[3]=f2bf(x0.w);
      pa[4]=f2bf(x1.x); pa[5]=f2bf(x1.y); pa[6]=f2bf(x1.z); pa[7]=f2bf(x1.w);
      pb[0]=f2bf(y0.x); pb[1]=f2bf(y0.y); pb[2]=f2bf(y0.z); pb[3]=f2bf(y0.w);
      pb[4]=f2bf(y1.x); pb[5]=f2bf(y1.y); pb[6]=f2bf(y1.z); pb[7]=f2bf(y1.w);
      *(short8*)(&Al[nb][tid*8])       = pa;
      *(short8*)(&Al[nb][(tid+256)*8]) = pb;
    }
    __syncthreads();
  }

  // epilogue: f = tanh(relu(c + bk[n])) * We_k[n]; reduce over block cols.
  // acc[mi][ni][r] -> row m0 + wm*64+mi*16+quad*4+r, col n0 + wn*64+ni*16+l16
  float esum[16];
#pragma unroll
  for (int q = 0; q < 16; ++q) esum[q] = 0.f;
#pragma unroll
  for (int ni = 0; ni < 4; ++ni) {
    const int n = n0 + wn*64 + ni*16 + l16;
    const float bkv = bk[n];
    const float wev = We[D + n];
#pragma unroll
    for (int mi = 0; mi < 4; ++mi)
#pragma unroll
      for (int r = 0; r < 4; ++r) {
        float x = acc[mi][ni][r] + bkv;
        x = fmaxf(x, 0.f);
        float ex = __expf(2.f * x);
        float th = 1.f - 2.f/(ex + 1.f);
        esum[mi*4 + r] += th * wev;
      }
  }
#pragma unroll
  for (int dd = 1; dd < 16; dd <<= 1)
#pragma unroll
    for (int q = 0; q < 16; ++q)
      esum[q] += __shfl_xor(esum[q], dd, 64);

  float* red = (float*)&Al[0][0];   // [128 rows][2 wn]
  if (l16 == 0) {
#pragma unroll
    for (int mi = 0; mi < 4; ++mi)
#pragma unroll
      for (int r = 0; r < 4; ++r)
        red[(wm*64 + mi*16 + quad*4 + r)*2 + wn] = esum[mi*4 + r];
  }
  __syncthreads();
  if (tid < 128)
    atomicAdd(eout + m0 + tid, red[tid*2] + red[tid*2 + 1]);
}

// ---------------- Kernel 3: in-place row softmax over s=2048 ----------------
__global__ __launch_bounds__(256) void softmax_rows(float* __restrict__ e) {
  const int b = blockIdx.x, t = threadIdx.x;
  __shared__ float red[256];
  float v[8];
  float m = -1e30f;
#pragma unroll
  for (int j = 0; j < 8; ++j) {
    v[j] = e[(size_t)b*SLEN + j*256 + t];
    m = fmaxf(m, v[j]);
  }
  red[t] = m; __syncthreads();
  for (int s = 128; s > 0; s >>= 1) {
    if (t < s) red[t] = fmaxf(red[t], red[t+s]);
    __syncthreads();
  }
  m = red[0];
  __syncthreads();
  float sum = 0.f;
#pragma unroll
  for (int j = 0; j < 8; ++j) { v[j] = __expf(v[j] - m); sum += v[j]; }
  red[t] = sum; __syncthreads();
  for (int s = 128; s > 0; s >>= 1) {
    if (t < s) red[t] += red[t+s];
    __syncthreads();
  }
  const float inv = 1.f / red[0];
#pragma unroll
  for (int j = 0; j < 8; ++j)
    e[(size_t)b*SLEN + j*256 + t] = v[j] * inv;
}

// ---------------- Kernel 4a: attn partials (no atomics) ----------------
// part[(b*16+sc)*1024 + d] = sum_{s in chunk} w[b,s]*states[b,s,d]
__global__ __launch_bounds__(256) void attn_partial(
    const float* __restrict__ states, const float* __restrict__ wts,
    float* __restrict__ part)
{
  const int sc = blockIdx.x;   // 0..15 (128 s each)
  const int b  = blockIdx.y;   // 0..15
  const int t  = threadIdx.x;
  __shared__ float wsh[128];
  if (t < 128) wsh[t] = wts[(size_t)b*SLEN + sc*128 + t];
  __syncthreads();
  const float* sp = states + ((size_t)b*SLEN + sc*128)*D + t*4;
  float ax = 0.f, ay = 0.f, az = 0.f, aw = 0.f;
#pragma unroll 8
  for (int s = 0; s < 128; ++s) {
    float4 v = *(const float4*)(sp + (size_t)s*D);
    const float wv = wsh[s];
    ax = fmaf(wv, v.x, ax);
    ay = fmaf(wv, v.y, ay);
    az = fmaf(wv, v.z, az);
    aw = fmaf(wv, v.w, aw);
  }
  float4 o; o.x = ax; o.y = ay; o.z = az; o.w = aw;
  *(float4*)(part + ((size_t)(b*16 + sc))*D + t*4) = o;
}

// ---------------- Kernel 4b: reduce 16 partials per batch ----------------
__global__ __launch_bounds__(256) void attn_final(
    const float* __restrict__ part, float* __restrict__ attn)
{
  const int b = blockIdx.x, t = threadIdx.x;
  float4 s = {0.f, 0.f, 0.f, 0.f};
#pragma unroll
  for (int sc = 0; sc < 16; ++sc) {
    float4 v = *(const float4*)(part + ((size_t)(b*16 + sc))*D + t*4);
    s.x += v.x; s.y += v.y; s.z += v.z; s.w += v.w;
  }
  *(float4*)(attn + (size_t)b*D + t*4) = s;
}

extern "C" void kernel_launch(void* const* d_in, const int* in_sizes, int n_in,
                              void* d_out, int out_size, void* d_ws, size_t ws_size,
                              hipStream_t stream) {
  // inputs: 0=query 1=states 2=Wq 3=bq 4=Wk 5=bk 6=We 7=be
  // q-path terms are constant per softmax row -> cancel; dead code.
  const float* states = (const float*)d_in[1];
  const float* Wk     = (const float*)d_in[4];
  const float* bk     = (const float*)d_in[5];
  const float* We     = (const float*)d_in[6];
  float* out = (float*)d_out;            // [0:32768) attn_weights, [32768:49152) attn
  short* WkT  = (short*)d_ws;            // 2 MB bf16 blocked scratch
  float* part = (float*)((char*)d_ws + (size_t)D*D*sizeof(short));  // 1 MB partials

  (void)in_sizes; (void)n_in; (void)out_size; (void)ws_size;

  hipMemsetAsync(out, 0, (size_t)MROWS*sizeof(float), stream);
  wk_prep<<<128, 256, 0, stream>>>(Wk, WkT);
  energy_gemm<<<2048, 256, 0, stream>>>(states, WkT, bk, We, out);
  softmax_rows<<<BS, 256, 0, stream>>>(out);
  attn_partial<<<dim3(16, BS), 256, 0, stream>>>(states, out, part);
  attn_final<<<BS, 256, 0, stream>>>(part, out + MROWS);
}

// Round 4
// 299.524 us; speedup vs baseline: 1.2690x; 1.2686x over previous
//
#include <hip/hip_runtime.h>
#include <hip/hip_bf16.h>

#define D 1024
#define SLEN 2048
#define BS 16
#define MROWS (BS*SLEN)   // 32768

typedef __attribute__((ext_vector_type(8))) short short8;
typedef __attribute__((ext_vector_type(4))) float f32x4;

__device__ __forceinline__ short f2bf(float f) {
  __hip_bfloat16 h = __float2bfloat16(f);
  return __builtin_bit_cast(short, h);
}

// ---------------- Kernel 1: Wk (k,n) fp32 -> blocked bf16 WkT ----------------
// WkT[(u*1024 + n)*8 + j] = bf16(Wk[(u*8+j)*1024 + n]), u=0..127.
// 16B slot (u,n) = B[n][k=u*8..u*8+7] = one MFMA B k-unit.
__global__ __launch_bounds__(256) void wk_prep(const float* __restrict__ Wk,
                                               short* __restrict__ WkT) {
  const int g = blockIdx.x;        // 0..127
  const int t = threadIdx.x;
#pragma unroll
  for (int it = 0; it < 4; ++it) {
    const int n = it*256 + t;
    short8 p;
#pragma unroll
    for (int j = 0; j < 8; ++j)
      p[j] = f2bf(Wk[(size_t)(g*8 + j)*D + n]);
    *(short8*)(WkT + ((size_t)g*D + n)*8) = p;
  }
}

// ---------------- Kernel 2: energy GEMM, barrier-free K-loop ----------------
// Block = 64 M-rows x full K in LDS (staged once, bf16, padded row stride 129
// slots -> conflict-free b128 on both write and read). 8 waves x 128 cols
// cover N=1024, so each block emits complete e rows (no atomics).
// B streamed L2->registers (WkT blocked layout), prefetched 1 k-step ahead;
// NO __syncthreads in the K-loop -> compiler emits fine-grained vmcnt.
__global__ __launch_bounds__(512, 2) void energy_gemm(
    const float* __restrict__ states, const short* __restrict__ WkT,
    const float* __restrict__ bk, const float* __restrict__ We,
    float* __restrict__ eraw)
{
  __shared__ short Al[64 * 129 * 8];   // 132 KB: slot(row,u) = row*129 + u

  const int tid  = threadIdx.x;
  const int w    = tid >> 6;        // wave 0..7 -> col group w*128
  const int lane = tid & 63;
  const int quad = lane >> 4;       // k-unit within 32-chunk
  const int l16  = lane & 15;
  const int m0   = blockIdx.x * 64;

  // ---- one-time A staging: 64 rows x 1024 k, fp32 -> bf16 ----
  // thread t: row = t>>3, u = (t&7) + i*8  (i = 0..15)
  // global: coalesced 32B-stride float4 pairs; LDS: (row + u) % 8 uniform
  // across lanes -> conflict-free ds_write_b128.
  {
    const int row = tid >> 3;
    const int u0  = tid & 7;
    const float* Ag = states + (size_t)(m0 + row)*D;
#pragma unroll
    for (int i = 0; i < 16; ++i) {
      const int u = u0 + i*8;
      float4 x0 = *(const float4*)(Ag + u*8);
      float4 x1 = *(const float4*)(Ag + u*8 + 4);
      short8 p;
      p[0]=f2bf(x0.x); p[1]=f2bf(x0.y); p[2]=f2bf(x0.z); p[3]=f2bf(x0.w);
      p[4]=f2bf(x1.x); p[5]=f2bf(x1.y); p[6]=f2bf(x1.z); p[7]=f2bf(x1.w);
      *(short8*)(Al + ((size_t)row*129 + u)*8) = p;
    }
  }
  __syncthreads();

  f32x4 acc[2][4][4];
#pragma unroll
  for (int nc = 0; nc < 2; ++nc)
#pragma unroll
    for (int mi = 0; mi < 4; ++mi)
#pragma unroll
      for (int ni = 0; ni < 4; ++ni)
        acc[nc][mi][ni] = (f32x4){0.f, 0.f, 0.f, 0.f};

  // per-lane bases
  const short* bbase = WkT + ((size_t)quad*D + w*128 + l16)*8;   // + ks*32768 + nc*512 + ni*128
  const short* abase = Al + ((size_t)l16*129 + quad)*8;          // + mi*16512 + ks*32

#define LOADB(ks, buf)                                                   \
  {                                                                      \
    const short* bp = bbase + (size_t)(ks)*32768;                        \
    _Pragma("unroll")                                                    \
    for (int nc = 0; nc < 2; ++nc)                                       \
      _Pragma("unroll")                                                  \
      for (int ni = 0; ni < 4; ++ni)                                     \
        buf[nc*4 + ni] = *(const short8*)(bp + nc*512 + ni*128);         \
  }

#define LOADA(ks, buf)                                                   \
  {                                                                      \
    _Pragma("unroll")                                                    \
    for (int mi = 0; mi < 4; ++mi)                                       \
      buf[mi] = *(const short8*)(abase + mi*16512 + (ks)*32);            \
  }

#define MFMAS(fa, fb)                                                    \
  {                                                                      \
    _Pragma("unroll")                                                    \
    for (int nc = 0; nc < 2; ++nc)                                       \
      _Pragma("unroll")                                                  \
      for (int mi = 0; mi < 4; ++mi)                                     \
        _Pragma("unroll")                                                \
        for (int ni = 0; ni < 4; ++ni)                                   \
          acc[nc][mi][ni] = __builtin_amdgcn_mfma_f32_16x16x32_bf16(     \
              fa[mi], fb[nc*4 + ni], acc[nc][mi][ni], 0, 0, 0);          \
  }

  short8 fa0[4], fa1[4], fb0[8], fb1[8];
  LOADA(0, fa0); LOADB(0, fb0);
#pragma unroll
  for (int kk = 0; kk < 16; ++kk) {
    LOADA(2*kk + 1, fa1); LOADB(2*kk + 1, fb1);
    MFMAS(fa0, fb0);
    if (kk < 15) { LOADA(2*kk + 2, fa0); LOADB(2*kk + 2, fb0); }
    MFMAS(fa1, fb1);
  }

  // ---- epilogue: esum[row] += tanh(relu(c + bk[n])) * We_k[n] ----
  // C/D: local row = mi*16 + quad*4 + r, col = w*128 + nc*64 + ni*16 + l16
  float esum[16];
#pragma unroll
  for (int q = 0; q < 16; ++q) esum[q] = 0.f;
#pragma unroll
  for (int nc = 0; nc < 2; ++nc)
#pragma unroll
    for (int ni = 0; ni < 4; ++ni) {
      const int n = w*128 + nc*64 + ni*16 + l16;
      const float bkv = bk[n];
      const float wev = We[D + n];
#pragma unroll
      for (int mi = 0; mi < 4; ++mi)
#pragma unroll
        for (int r = 0; r < 4; ++r) {
          float x = acc[nc][mi][ni][r] + bkv;
          x = fmaxf(x, 0.f);
          float ex = __expf(2.f * x);
          float th = 1.f - 2.f/(ex + 1.f);
          esum[mi*4 + r] += th * wev;
        }
    }
  // reduce across the 16 cols held by l16 (xor stays within the quad)
#pragma unroll
  for (int dd = 1; dd < 16; dd <<= 1)
#pragma unroll
    for (int q = 0; q < 16; ++q)
      esum[q] += __shfl_xor(esum[q], dd, 64);

  __syncthreads();                    // all waves done reading Al
  float* red = (float*)Al;            // [64 rows][8 waves]
  if (l16 == 0) {
#pragma unroll
    for (int mi = 0; mi < 4; ++mi)
#pragma unroll
      for (int r = 0; r < 4; ++r)
        red[(mi*16 + quad*4 + r)*8 + w] = esum[mi*4 + r];
  }
  __syncthreads();
  if (tid < 64) {
    float s = 0.f;
#pragma unroll
    for (int wi = 0; wi < 8; ++wi) s += red[tid*8 + wi];
    eraw[m0 + tid] = s;
  }
#undef LOADB
#undef LOADA
#undef MFMAS
}

// ------- Kernel 3: fused softmax + attn partials (no separate softmax) ------
// Block (sc, b): redundantly reduces the full e row (2048) for max/sum, then
// writes normalized weights for its own 128-s chunk and the attn partial.
__global__ __launch_bounds__(256) void attn_sm_partial(
    const float* __restrict__ states, const float* __restrict__ eraw,
    float* __restrict__ wts, float* __restrict__ part)
{
  const int sc = blockIdx.x;   // 0..15
  const int b  = blockIdx.y;   // 0..15
  const int t  = threadIdx.x;
  __shared__ float red[256];
  __shared__ float wsh[128];

  float v[8];
  float m = -1e30f;
#pragma unroll
  for (int j = 0; j < 8; ++j) {
    v[j] = eraw[(size_t)b*SLEN + j*256 + t];
    m = fmaxf(m, v[j]);
  }
  red[t] = m; __syncthreads();
  for (int s = 128; s > 0; s >>= 1) {
    if (t < s) red[t] = fmaxf(red[t], red[t+s]);
    __syncthreads();
  }
  m = red[0];
  __syncthreads();
  float sum = 0.f;
#pragma unroll
  for (int j = 0; j < 8; ++j) sum += __expf(v[j] - m);
  red[t] = sum; __syncthreads();
  for (int s = 128; s > 0; s >>= 1) {
    if (t < s) red[t] += red[t+s];
    __syncthreads();
  }
  const float inv = 1.f / red[0];

  if (t < 128) {
    const float wv = __expf(eraw[(size_t)b*SLEN + sc*128 + t] - m) * inv;
    wts[(size_t)b*SLEN + sc*128 + t] = wv;
    wsh[t] = wv;
  }
  __syncthreads();

  const float* sp = states + ((size_t)b*SLEN + sc*128)*D + t*4;
  float ax = 0.f, ay = 0.f, az = 0.f, aw = 0.f;
#pragma unroll 8
  for (int s = 0; s < 128; ++s) {
    float4 x = *(const float4*)(sp + (size_t)s*D);
    const float wv = wsh[s];
    ax = fmaf(wv, x.x, ax);
    ay = fmaf(wv, x.y, ay);
    az = fmaf(wv, x.z, az);
    aw = fmaf(wv, x.w, aw);
  }
  float4 o; o.x = ax; o.y = ay; o.z = az; o.w = aw;
  *(float4*)(part + ((size_t)(b*16 + sc))*D + t*4) = o;
}

// ---------------- Kernel 4: reduce 16 partials per batch ----------------
__global__ __launch_bounds__(256) void attn_final(
    const float* __restrict__ part, float* __restrict__ attn)
{
  const int b = blockIdx.x, t = threadIdx.x;
  float4 s = {0.f, 0.f, 0.f, 0.f};
#pragma unroll
  for (int sc = 0; sc < 16; ++sc) {
    float4 v = *(const float4*)(part + ((size_t)(b*16 + sc))*D + t*4);
    s.x += v.x; s.y += v.y; s.z += v.z; s.w += v.w;
  }
  *(float4*)(attn + (size_t)b*D + t*4) = s;
}

extern "C" void kernel_launch(void* const* d_in, const int* in_sizes, int n_in,
                              void* d_out, int out_size, void* d_ws, size_t ws_size,
                              hipStream_t stream) {
  // inputs: 0=query 1=states 2=Wq 3=bq 4=Wk 5=bk 6=We 7=be
  // q-path terms are constant per softmax row -> cancel; dead code.
  const float* states = (const float*)d_in[1];
  const float* Wk     = (const float*)d_in[4];
  const float* bk     = (const float*)d_in[5];
  const float* We     = (const float*)d_in[6];
  float* out = (float*)d_out;            // [0:32768) attn_weights, [32768:49152) attn

  short* WkT  = (short*)d_ws;                                   // 2 MB
  float* part = (float*)((char*)d_ws + (size_t)D*D*sizeof(short));        // 1 MB
  float* eraw = (float*)((char*)d_ws + (size_t)D*D*sizeof(short)
                                     + (size_t)BS*16*D*sizeof(float));    // 128 KB

  (void)in_sizes; (void)n_in; (void)out_size; (void)ws_size;

  wk_prep<<<128, 256, 0, stream>>>(Wk, WkT);
  energy_gemm<<<MROWS/64, 512, 0, stream>>>(states, WkT, bk, We, eraw);
  attn_sm_partial<<<dim3(16, BS), 256, 0, stream>>>(states, eraw, out, part);
  attn_final<<<BS, 256, 0, stream>>>(part, out + MROWS);
}

// Round 5
// 290.198 us; speedup vs baseline: 1.3098x; 1.0321x over previous
//
#include <hip/hip_runtime.h>
#include <hip/hip_bf16.h>

#define D 1024
#define SLEN 2048
#define BS 16
#define MROWS (BS*SLEN)   // 32768

typedef __attribute__((ext_vector_type(8))) short short8;
typedef __attribute__((ext_vector_type(4))) float f32x4;

__device__ __forceinline__ short f2bf(float f) {
  __hip_bfloat16 h = __float2bfloat16(f);
  return __builtin_bit_cast(short, h);
}

// non-temporal float4 load: states is pure streaming (zero reuse) -> bypass
// L2/L3 so the 2 MB WkT stays L2-resident for the B stream.
__device__ __forceinline__ float4 ntload4(const float* p) {
  f32x4 v = __builtin_nontemporal_load((const f32x4*)p);
  float4 r; r.x = v.x; r.y = v.y; r.z = v.z; r.w = v.w; return r;
}

// ---------------- Kernel 1: Wk (k,n) fp32 -> blocked bf16 WkT ----------------
// WkT[(u*1024 + n)*8 + j] = bf16(Wk[(u*8+j)*1024 + n]), u=0..127.
// 16B slot (u,n) = B[n][k=u*8..u*8+7] = one MFMA B k-unit.
__global__ __launch_bounds__(256) void wk_prep(const float* __restrict__ Wk,
                                               short* __restrict__ WkT) {
  const int g = blockIdx.x;        // 0..127
  const int t = threadIdx.x;
#pragma unroll
  for (int it = 0; it < 4; ++it) {
    const int n = it*256 + t;
    short8 p;
#pragma unroll
    for (int j = 0; j < 8; ++j)
      p[j] = f2bf(Wk[(size_t)(g*8 + j)*D + n]);
    *(short8*)(WkT + ((size_t)g*D + n)*8) = p;
  }
}

// ---------------- Kernel 2: energy GEMM, barrier-free K-loop ----------------
// Block = 64 M-rows x full K in LDS (staged once, bf16, padded row stride 129
// slots). 8 waves x 128 cols cover N=1024 -> complete e rows, no atomics.
// B streamed L2->registers, prefetched 1 k-step ahead, no barriers in K-loop.
// A staged with NON-TEMPORAL loads (streaming) to protect WkT's L2 residency.
// Blocks 0..15 also zero-init the attn output (consumed by the next kernel).
__global__ __launch_bounds__(512, 2) void energy_gemm(
    const float* __restrict__ states, const short* __restrict__ WkT,
    const float* __restrict__ bk, const float* __restrict__ We,
    float* __restrict__ eraw, float* __restrict__ attn)
{
  __shared__ short Al[64 * 129 * 8];   // 132 KB: slot(row,u) = row*129 + u

  const int tid  = threadIdx.x;
  const int w    = tid >> 6;        // wave 0..7 -> col group w*128
  const int lane = tid & 63;
  const int quad = lane >> 4;       // k-unit within 32-chunk
  const int l16  = lane & 15;
  const int m0   = blockIdx.x * 64;

  // zero-init attn region (read-modify-write target of attn_sm_partial)
  if (blockIdx.x < BS && tid < 256) {
    f32x4 z = {0.f, 0.f, 0.f, 0.f};
    *(f32x4*)(attn + (size_t)blockIdx.x*D + tid*4) = z;
  }

  // ---- one-time A staging: 64 rows x 1024 k, fp32 -> bf16 (non-temporal) ----
  {
    const int row = tid >> 3;
    const int u0  = tid & 7;
    const float* Ag = states + (size_t)(m0 + row)*D;
#pragma unroll
    for (int i = 0; i < 16; ++i) {
      const int u = u0 + i*8;
      float4 x0 = ntload4(Ag + u*8);
      float4 x1 = ntload4(Ag + u*8 + 4);
      short8 p;
      p[0]=f2bf(x0.x); p[1]=f2bf(x0.y); p[2]=f2bf(x0.z); p[3]=f2bf(x0.w);
      p[4]=f2bf(x1.x); p[5]=f2bf(x1.y); p[6]=f2bf(x1.z); p[7]=f2bf(x1.w);
      *(short8*)(Al + ((size_t)row*129 + u)*8) = p;
    }
  }
  __syncthreads();

  f32x4 acc[2][4][4];
#pragma unroll
  for (int nc = 0; nc < 2; ++nc)
#pragma unroll
    for (int mi = 0; mi < 4; ++mi)
#pragma unroll
      for (int ni = 0; ni < 4; ++ni)
        acc[nc][mi][ni] = (f32x4){0.f, 0.f, 0.f, 0.f};

  const short* bbase = WkT + ((size_t)quad*D + w*128 + l16)*8;   // + ks*32768 + nc*512 + ni*128
  const short* abase = Al + ((size_t)l16*129 + quad)*8;          // + mi*16512 + ks*32

#define LOADB(ks, buf)                                                   \
  {                                                                      \
    const short* bp = bbase + (size_t)(ks)*32768;                        \
    _Pragma("unroll")                                                    \
    for (int nc = 0; nc < 2; ++nc)                                       \
      _Pragma("unroll")                                                  \
      for (int ni = 0; ni < 4; ++ni)                                     \
        buf[nc*4 + ni] = *(const short8*)(bp + nc*512 + ni*128);         \
  }

#define LOADA(ks, buf)                                                   \
  {                                                                      \
    _Pragma("unroll")                                                    \
    for (int mi = 0; mi < 4; ++mi)                                       \
      buf[mi] = *(const short8*)(abase + mi*16512 + (ks)*32);            \
  }

#define MFMAS(fa, fb)                                                    \
  {                                                                      \
    _Pragma("unroll")                                                    \
    for (int nc = 0; nc < 2; ++nc)                                       \
      _Pragma("unroll")                                                  \
      for (int mi = 0; mi < 4; ++mi)                                     \
        _Pragma("unroll")                                                \
        for (int ni = 0; ni < 4; ++ni)                                   \
          acc[nc][mi][ni] = __builtin_amdgcn_mfma_f32_16x16x32_bf16(     \
              fa[mi], fb[nc*4 + ni], acc[nc][mi][ni], 0, 0, 0);          \
  }

  short8 fa0[4], fa1[4], fb0[8], fb1[8];
  LOADA(0, fa0); LOADB(0, fb0);
#pragma unroll
  for (int kk = 0; kk < 16; ++kk) {
    LOADA(2*kk + 1, fa1); LOADB(2*kk + 1, fb1);
    MFMAS(fa0, fb0);
    if (kk < 15) { LOADA(2*kk + 2, fa0); LOADB(2*kk + 2, fb0); }
    MFMAS(fa1, fb1);
  }

  // ---- epilogue: esum[row] += tanh(relu(c + bk[n])) * We_k[n] ----
  float esum[16];
#pragma unroll
  for (int q = 0; q < 16; ++q) esum[q] = 0.f;
#pragma unroll
  for (int nc = 0; nc < 2; ++nc)
#pragma unroll
    for (int ni = 0; ni < 4; ++ni) {
      const int n = w*128 + nc*64 + ni*16 + l16;
      const float bkv = bk[n];
      const float wev = We[D + n];
#pragma unroll
      for (int mi = 0; mi < 4; ++mi)
#pragma unroll
        for (int r = 0; r < 4; ++r) {
          float x = acc[nc][mi][ni][r] + bkv;
          x = fmaxf(x, 0.f);
          float ex = __expf(2.f * x);
          float th = 1.f - 2.f/(ex + 1.f);
          esum[mi*4 + r] += th * wev;
        }
    }
#pragma unroll
  for (int dd = 1; dd < 16; dd <<= 1)
#pragma unroll
    for (int q = 0; q < 16; ++q)
      esum[q] += __shfl_xor(esum[q], dd, 64);

  __syncthreads();                    // all waves done reading Al
  float* red = (float*)Al;            // [64 rows][8 waves]
  if (l16 == 0) {
#pragma unroll
    for (int mi = 0; mi < 4; ++mi)
#pragma unroll
      for (int r = 0; r < 4; ++r)
        red[(mi*16 + quad*4 + r)*8 + w] = esum[mi*4 + r];
  }
  __syncthreads();
  if (tid < 64) {
    float s = 0.f;
#pragma unroll
    for (int wi = 0; wi < 8; ++wi) s += red[tid*8 + wi];
    eraw[m0 + tid] = s;
  }
#undef LOADB
#undef LOADA
#undef MFMAS
}

// ------- Kernel 3: fused softmax + attn partial w/ direct atomic add --------
// Block (sc, b): redundantly reduces the full e row (2048) for max/sum, then
// writes normalized weights for its 128-s chunk and atomicAdds its partial
// attn contribution (16 contenders per address).
__global__ __launch_bounds__(256) void attn_sm_partial(
    const float* __restrict__ states, const float* __restrict__ eraw,
    float* __restrict__ wts, float* __restrict__ attn)
{
  const int sc = blockIdx.x;   // 0..15
  const int b  = blockIdx.y;   // 0..15
  const int t  = threadIdx.x;
  __shared__ float red[256];
  __shared__ float wsh[128];

  float v[8];
  float m = -1e30f;
#pragma unroll
  for (int j = 0; j < 8; ++j) {
    v[j] = eraw[(size_t)b*SLEN + j*256 + t];
    m = fmaxf(m, v[j]);
  }
  red[t] = m; __syncthreads();
  for (int s = 128; s > 0; s >>= 1) {
    if (t < s) red[t] = fmaxf(red[t], red[t+s]);
    __syncthreads();
  }
  m = red[0];
  __syncthreads();
  float sum = 0.f;
#pragma unroll
  for (int j = 0; j < 8; ++j) sum += __expf(v[j] - m);
  red[t] = sum; __syncthreads();
  for (int s = 128; s > 0; s >>= 1) {
    if (t < s) red[t] += red[t+s];
    __syncthreads();
  }
  const float inv = 1.f / red[0];

  if (t < 128) {
    const float wv = __expf(eraw[(size_t)b*SLEN + sc*128 + t] - m) * inv;
    wts[(size_t)b*SLEN + sc*128 + t] = wv;
    wsh[t] = wv;
  }
  __syncthreads();

  const float* sp = states + ((size_t)b*SLEN + sc*128)*D + t*4;
  float ax = 0.f, ay = 0.f, az = 0.f, aw = 0.f;
#pragma unroll 8
  for (int s = 0; s < 128; ++s) {
    float4 x = ntload4(sp + (size_t)s*D);
    const float wv = wsh[s];
    ax = fmaf(wv, x.x, ax);
    ay = fmaf(wv, x.y, ay);
    az = fmaf(wv, x.z, az);
    aw = fmaf(wv, x.w, aw);
  }
  float* o = attn + (size_t)b*D + t*4;
  atomicAdd(o+0, ax); atomicAdd(o+1, ay);
  atomicAdd(o+2, az); atomicAdd(o+3, aw);
}

extern "C" void kernel_launch(void* const* d_in, const int* in_sizes, int n_in,
                              void* d_out, int out_size, void* d_ws, size_t ws_size,
                              hipStream_t stream) {
  // inputs: 0=query 1=states 2=Wq 3=bq 4=Wk 5=bk 6=We 7=be
  // q-path terms are constant per softmax row -> cancel; dead code.
  const float* states = (const float*)d_in[1];
  const float* Wk     = (const float*)d_in[4];
  const float* bk     = (const float*)d_in[5];
  const float* We     = (const float*)d_in[6];
  float* out = (float*)d_out;            // [0:32768) attn_weights, [32768:49152) attn

  short* WkT  = (short*)d_ws;                                   // 2 MB
  float* eraw = (float*)((char*)d_ws + (size_t)D*D*sizeof(short));  // 128 KB

  (void)in_sizes; (void)n_in; (void)out_size; (void)ws_size;

  wk_prep<<<128, 256, 0, stream>>>(Wk, WkT);
  energy_gemm<<<MROWS/64, 512, 0, stream>>>(states, WkT, bk, We, eraw, out + MROWS);
  attn_sm_partial<<<dim3(16, BS), 256, 0, stream>>>(states, eraw, out, out + MROWS);
}